// Round 6
// baseline (374.378 us; speedup 1.0000x reference)
//
#include <hip/hip_runtime.h>
#include <hip/hip_bf16.h>
#include <math.h>

#define HIDDEN 256
#define INV_SCALE 0.17677669529663687f  /* 1/sqrt(32) */

typedef __attribute__((ext_vector_type(8))) short short8;
typedef __attribute__((ext_vector_type(4))) float f32x4;
typedef const __attribute__((address_space(1))) unsigned int* gas_ptr;
typedef __attribute__((address_space(3))) unsigned int* las_ptr;

static __device__ __forceinline__ unsigned short f2bf(float x) {
  unsigned u = __float_as_uint(x);
  unsigned r = (u + 0x7FFF + ((u >> 16) & 1)) >> 16;
  return (unsigned short)r;
}
static __device__ __forceinline__ float bf2f(unsigned short u) {
  return __uint_as_float((unsigned)u << 16);
}

#define GLL(gp, lp) __builtin_amdgcn_global_load_lds((gas_ptr)(const void*)(gp), (las_ptr)(void*)(lp), 16, 0, 0)

// ---------------- input / weight conversion to bf16 ----------------

__global__ __launch_bounds__(256) void conv_a_kernel(const float* __restrict__ in,
                                                     unsigned short* __restrict__ out,
                                                     int total4) {
  int stride = gridDim.x * blockDim.x;
  for (int i = blockIdx.x * blockDim.x + threadIdx.x; i < total4; i += stride) {
    float4 f = ((const float4*)in)[i];
    ushort4 u;
    u.x = f2bf(f.x); u.y = f2bf(f.y); u.z = f2bf(f.z); u.w = f2bf(f.w);
    ((ushort4*)out)[i] = u;
  }
}

// Wq,Wk,Wv -> wqkv[768][256], Wo -> wob[256][256]
__global__ __launch_bounds__(256) void conv_w_kernel(const float* __restrict__ Wq,
                                                     const float* __restrict__ Wk,
                                                     const float* __restrict__ Wv,
                                                     const float* __restrict__ Wo,
                                                     unsigned short* __restrict__ wqkv,
                                                     unsigned short* __restrict__ wob) {
  int i = blockIdx.x * 256 + threadIdx.x;  // grid 1024 -> 262144
  int m = i >> 16;
  int j = i & 65535;
  const float* s = (m == 0) ? Wq : (m == 1) ? Wk : (m == 2) ? Wv : Wo;
  unsigned short b = f2bf(s[j]);
  if (m < 3) wqkv[m * 65536 + j] = b;
  else wob[j] = b;
}

// ---------------- CSR build ----------------

__global__ __launch_bounds__(256) void hist_kernel(const int* __restrict__ dst,
                                                   int* __restrict__ deg, int E) {
  int e = blockIdx.x * blockDim.x + threadIdx.x;
  if (e < E) atomicAdd(&deg[dst[e]], 1);
}

__global__ __launch_bounds__(256) void scan1_kernel(const int* __restrict__ deg,
                                                    int* __restrict__ offs,
                                                    int* __restrict__ bsums, int N) {
  __shared__ int s[256];
  int tid = threadIdx.x;
  int base = blockIdx.x * 1024 + tid * 4;
  int v0 = (base + 0 < N) ? deg[base + 0] : 0;
  int v1 = (base + 1 < N) ? deg[base + 1] : 0;
  int v2 = (base + 2 < N) ? deg[base + 2] : 0;
  int v3 = (base + 3 < N) ? deg[base + 3] : 0;
  int tsum = v0 + v1 + v2 + v3;
  s[tid] = tsum;
  __syncthreads();
  for (int off = 1; off < 256; off <<= 1) {
    int t = (tid >= off) ? s[tid - off] : 0;
    __syncthreads();
    s[tid] += t;
    __syncthreads();
  }
  int excl = s[tid] - tsum;
  if (base + 0 < N) offs[base + 0] = excl;
  if (base + 1 < N) offs[base + 1] = excl + v0;
  if (base + 2 < N) offs[base + 2] = excl + v0 + v1;
  if (base + 3 < N) offs[base + 3] = excl + v0 + v1 + v2;
  if (tid == 255) bsums[blockIdx.x] = s[255];
}

__global__ void scan2_kernel(int* __restrict__ bsums, int nb) {
  if (blockIdx.x == 0 && threadIdx.x == 0) {
    int run = 0;
    for (int b = 0; b < nb; ++b) { int t = bsums[b]; bsums[b] = run; run += t; }
  }
}

__global__ __launch_bounds__(256) void scan3_kernel(int* __restrict__ offs,
                                                    int* __restrict__ cursor,
                                                    const int* __restrict__ bsums,
                                                    int N, int E) {
  int i = blockIdx.x * blockDim.x + threadIdx.x;
  if (i < N) {
    int v = offs[i] + bsums[i >> 10];
    offs[i] = v;
    cursor[i] = v;
  }
  if (i == 0) offs[N] = E;
}

__global__ __launch_bounds__(256) void scatter_kernel(const int* __restrict__ dst,
                                                      const int* __restrict__ src,
                                                      int* __restrict__ cursor,
                                                      int* __restrict__ esrc, int E) {
  int e = blockIdx.x * blockDim.x + threadIdx.x;
  if (e < E) {
    int n = dst[e];
    int pos = atomicAdd(&cursor[n], 1);
    esrc[pos] = src[e];
  }
}

// ---------------- bf16 MFMA GEMM (R2 serial-staging structure, 128x128) ----------------
// MODE 0: fused QKV (Ncols=768). Epilogue writes HEAD-MAJOR [h][N][32] bf16 for q,k,v.
// MODE 1: out projection (Ncols=256): fp32 + bias, row-major.
#define GBM 128
#define GBN 128
#define GBK 32

template <int MODE>
__global__ __launch_bounds__(256) void mfma_gemm_kernel(const unsigned short* __restrict__ A,
                                                        const unsigned short* __restrict__ B,
                                                        const float* __restrict__ bias,
                                                        float* __restrict__ Cf,
                                                        unsigned short* __restrict__ Cq,
                                                        unsigned short* __restrict__ Ck,
                                                        unsigned short* __restrict__ Cv,
                                                        int M, int N) {
  __shared__ unsigned short As[GBM][GBK];
  __shared__ unsigned short Bs[GBN][GBK];
  int tid = threadIdx.x;
  int lane = tid & 63;
  int wid = tid >> 6;
  int wm = wid >> 1, wn = wid & 1;
  int brow = blockIdx.x * GBM;
  int bcol = blockIdx.y * GBN;

  // staging: wave wid covers rows [wid*32, wid*32+32) in two 1KB calls
  int srow = wid * 32 + (lane >> 2);
  int skoff = (lane & 3) * 8;
  const unsigned short* gA0 = &A[(size_t)(brow + srow) * HIDDEN + skoff];
  const unsigned short* gB0 = &B[(size_t)(bcol + srow) * HIDDEN + skoff];
  char* ldsA = (char*)&As[0][0] + wid * 2048;
  char* ldsB = (char*)&Bs[0][0] + wid * 2048;

  f32x4 acc[4][4] = {};

  int fr = lane & 15;
  int kg = (lane >> 4) * 8;

  for (int k0 = 0; k0 < HIDDEN; k0 += GBK) {
    __syncthreads();
    GLL(gA0 + k0, ldsA); GLL(gA0 + k0 + 16 * HIDDEN, ldsA + 1024);
    GLL(gB0 + k0, ldsB); GLL(gB0 + k0 + 16 * HIDDEN, ldsB + 1024);
    asm volatile("s_waitcnt vmcnt(0)" ::: "memory");
    __syncthreads();
    short8 af[4], bfg[4];
#pragma unroll
    for (int mi = 0; mi < 4; ++mi)
      af[mi] = *(const short8*)&As[wm * 64 + mi * 16 + fr][kg];
#pragma unroll
    for (int ni = 0; ni < 4; ++ni)
      bfg[ni] = *(const short8*)&Bs[wn * 64 + ni * 16 + fr][kg];
#pragma unroll
    for (int mi = 0; mi < 4; ++mi)
#pragma unroll
      for (int ni = 0; ni < 4; ++ni)
        acc[mi][ni] = __builtin_amdgcn_mfma_f32_16x16x32_bf16(af[mi], bfg[ni], acc[mi][ni], 0, 0, 0);
  }

  int fq = lane >> 4;
#pragma unroll
  for (int mi = 0; mi < 4; ++mi) {
#pragma unroll
    for (int ni = 0; ni < 4; ++ni) {
      int c = bcol + wn * 64 + ni * 16 + fr;
#pragma unroll
      for (int j = 0; j < 4; ++j) {
        int r = brow + wm * 64 + mi * 16 + fq * 4 + j;
        if (r < M) {
          float val = acc[mi][ni][j];
          if (MODE == 1) {
            Cf[(size_t)r * HIDDEN + c] = val + bias[c];
          } else {
            // head-major [h][N][32] layout
            int cc = c & 255;
            size_t addr = ((size_t)(cc >> 5) * N + r) * 32 + (cc & 31);
            if (c < 256) Cq[addr] = f2bf(val + bias[c]);
            else if (c < 512) Ck[addr] = f2bf(val);
            else Cv[addr] = f2bf(val);
          }
        }
      }
    }
  }
}

// ---------------- per-(dst-node, head) attention aggregation ----------------
// blockIdx.x = chunk*8 + h  -> all blocks of head h land on XCD h (round-robin dispatch).
// 1 wave per (node, head). 16 edge-groups of 4 lanes; lane owns 8 channels of the
// 32-channel head slice. q/k/v are head-major [h][N][32].
__global__ __launch_bounds__(256) void agg_kernel(const unsigned short* __restrict__ qh,
                                                  const unsigned short* __restrict__ kh,
                                                  const unsigned short* __restrict__ vh,
                                                  const int* __restrict__ offs,
                                                  const int* __restrict__ esrc,
                                                  unsigned short* __restrict__ o, int N) {
  int h = blockIdx.x & 7;
  int chunk = blockIdx.x >> 3;
  int n = chunk * 4 + (threadIdx.x >> 6);
  if (n >= N) return;
  int lane = threadIdx.x & 63;
  int g = lane >> 2;        // edge group 0..15
  int cs = (lane & 3) * 8;  // channel slice within head

  size_t headbase = (size_t)h * N;

  float qf[8];
  {
    short8 qv = *(const short8*)&qh[(headbase + n) * 32 + cs];
#pragma unroll
    for (int j = 0; j < 8; ++j) qf[j] = bf2f((unsigned short)qv[j]);
  }

  int e0 = offs[n], e1 = offs[n + 1];
  float wv[8] = {};
  float z = 0.f;

  for (int b = e0; b < e1; b += 16) {
    int my = b + g;
    bool valid = my < e1;
    int s = esrc[valid ? my : (e1 - 1)];
    short8 kv = *(const short8*)&kh[(headbase + s) * 32 + cs];
    short8 vv = *(const short8*)&vh[(headbase + s) * 32 + cs];
    float d = 0.f;
#pragma unroll
    for (int j = 0; j < 8; ++j) d += qf[j] * bf2f((unsigned short)kv[j]);
    d += __shfl_xor(d, 1);
    d += __shfl_xor(d, 2);  // full 32-ch head dot in all 4 lanes of the group
    float e = valid ? __expf(fminf(fmaxf(d * INV_SCALE, -10.f), 10.f)) : 0.f;
#pragma unroll
    for (int j = 0; j < 8; ++j) wv[j] += e * bf2f((unsigned short)vv[j]);
    z += e;
  }

  // combine the 16 edge groups (xor over group bits only; channel bits 0-1 untouched)
#pragma unroll
  for (int m = 4; m < 64; m <<= 1) {
#pragma unroll
    for (int j = 0; j < 8; ++j) wv[j] += __shfl_xor(wv[j], m);
    z += __shfl_xor(z, m);
  }

  if (g == 0) {
    float inv = 1.0f / z;
    short8 ov;
#pragma unroll
    for (int j = 0; j < 8; ++j) ov[j] = (short)f2bf(wv[j] * inv);
    *(short8*)&o[(size_t)n * HIDDEN + h * 32 + cs] = ov;  // row-major for out-proj
  }
}

// ---------------- launch ----------------

extern "C" void kernel_launch(void* const* d_in, const int* in_sizes, int n_in,
                              void* d_out, int out_size, void* d_ws, size_t ws_size,
                              hipStream_t stream) {
  const float* inputs = (const float*)d_in[0];
  const float* Wq = (const float*)d_in[1];
  const float* bq = (const float*)d_in[2];
  const float* Wk = (const float*)d_in[3];
  const float* Wv = (const float*)d_in[4];
  const float* Wo = (const float*)d_in[5];
  const float* bo = (const float*)d_in[6];
  const int* src = (const int*)d_in[7];
  const int* dst = (const int*)d_in[8];

  int N = in_sizes[0] / HIDDEN;
  int E = in_sizes[7];
  int Mpad = N + GBM;  // pad rows so GEMM staging overrun stays in allocated ws

  char* w = (char*)d_ws;
  unsigned short* a_bf = (unsigned short*)w; w += (size_t)Mpad * HIDDEN * 2;
  unsigned short* qh = (unsigned short*)w;   w += (size_t)N * HIDDEN * 2;
  unsigned short* kh = (unsigned short*)w;   w += (size_t)N * HIDDEN * 2;
  unsigned short* vh = (unsigned short*)w;   w += (size_t)N * HIDDEN * 2;
  unsigned short* ob = (unsigned short*)w;   w += (size_t)Mpad * HIDDEN * 2;
  unsigned short* wqkv = (unsigned short*)w; w += (size_t)768 * HIDDEN * 2;
  unsigned short* wob = (unsigned short*)w;  w += (size_t)256 * HIDDEN * 2;
  int* deg = (int*)w;    w += (size_t)N * 4;
  int* offs = (int*)w;   w += (size_t)(N + 4) * 4;
  int* cursor = (int*)w; w += (size_t)N * 4;
  int* esrc = (int*)w;   w += (size_t)E * 4;
  int* bsums = (int*)w;  w += 256 * 4;

  // conversions
  conv_a_kernel<<<2048, 256, 0, stream>>>(inputs, a_bf, N * (HIDDEN / 4));
  conv_w_kernel<<<1024, 256, 0, stream>>>(Wq, Wk, Wv, Wo, wqkv, wob);

  // CSR build
  hipMemsetAsync(deg, 0, (size_t)N * 4, stream);
  int eb = (E + 255) / 256;
  hist_kernel<<<eb, 256, 0, stream>>>(dst, deg, E);
  int nb = (N + 1023) / 1024;
  scan1_kernel<<<nb, 256, 0, stream>>>(deg, offs, bsums, N);
  scan2_kernel<<<1, 64, 0, stream>>>(bsums, nb);
  scan3_kernel<<<(N + 255) / 256, 256, 0, stream>>>(offs, cursor, bsums, N, E);
  scatter_kernel<<<eb, 256, 0, stream>>>(dst, src, cursor, esrc, E);

  // fused QKV projection (bf16 MFMA), head-major epilogue
  dim3 gqkv((N + GBM - 1) / GBM, 768 / GBN);
  mfma_gemm_kernel<0><<<gqkv, 256, 0, stream>>>(a_bf, wqkv, bq, nullptr, qh, kh, vh, N, N);

  // attention aggregation: blockIdx = chunk*8 + head  (head -> XCD pinning)
  int chunks = (N + 3) / 4;
  agg_kernel<<<chunks * 8, 256, 0, stream>>>(qh, kh, vh, offs, esrc, ob, N);

  // output projection
  dim3 gout((N + GBM - 1) / GBM, 256 / GBN);
  mfma_gemm_kernel<1><<<gout, 256, 0, stream>>>(ob, wob, bo, (float*)d_out, nullptr, nullptr, nullptr, N, N);
}